// Round 1
// baseline (221.200 us; speedup 1.0000x reference)
//
#include <hip/hip_runtime.h>
#include <stdint.h>

// Problem constants: B=16, T=1024, N=512
#define BB 16
#define TT 1024
#define NN 512

typedef unsigned short u16;
typedef __bf16 bf16_t;
typedef bf16_t bf16x8 __attribute__((ext_vector_type(8)));
typedef float f32x4 __attribute__((ext_vector_type(4)));

struct alignas(8) U16x4 { u16 x, y, z, w; };
struct alignas(16) F32x4 { float x, y, z, w; };

__device__ __forceinline__ u16 f2bf(float f) {
    union { float f; uint32_t u; } v; v.f = f;
    uint32_t r = v.u + 0x7fffu + ((v.u >> 16) & 1u);
    return (u16)(r >> 16);
}

__device__ __forceinline__ void gload_lds16(const void* g, void* l) {
    __builtin_amdgcn_global_load_lds(
        (const __attribute__((address_space(1))) void*)g,
        (__attribute__((address_space(3))) void*)l, 16, 0, 0);
}

// ---------------------------------------------------------------------------
// fp32 -> bf16 (RTNE), vectorized x4
// ---------------------------------------------------------------------------
__global__ __launch_bounds__(256)
void cvt_f32_bf16(const float* __restrict__ in, u16* __restrict__ out, int n4) {
    int i = blockIdx.x * blockDim.x + threadIdx.x;
    int stride = gridDim.x * blockDim.x;
    for (int c = i; c < n4; c += stride) {
        F32x4 f = ((const F32x4*)in)[c];
        U16x4 u;
        u.x = f2bf(f.x); u.y = f2bf(f.y); u.z = f2bf(f.z); u.w = f2bf(f.w);
        ((U16x4*)out)[c] = u;
    }
}

// ---------------------------------------------------------------------------
// NT GEMM: C[i,j] = sum_k A[i,k] * Bt[j,k]   (A: [M,K] ld=lda, Bt: [Nc,K] ld=ldb)
// bf16 inputs (raw u16), fp32 accum. 128x128 tile, BK=64, 4 waves (2x2),
// each wave 4x4 frags of mfma_f32_16x16x32_bf16.
// LDS staged via global_load_lds(16B) with XOR-16B swizzle (source-side
// pre-swizzle, m173 pattern) -> ~2-way bank conflicts on ds_read_b128.
// MODE 0: bf16 natural store C[i*Nc+j]         (+ z*sC)
// MODE 1: bf16 transposed q-style store: out[((i>>10)*512 + j)*1024 + (i&1023)]
// MODE 2: fp32 natural store                    (+ z*sC)
// MODE 3: fp32 natural store + bias[j]
// ---------------------------------------------------------------------------
template<int MODE>
__global__ __launch_bounds__(256)
void gemm_nt(const u16* __restrict__ Ag, const u16* __restrict__ Bg,
             void* __restrict__ Cg, const float* __restrict__ bias,
             int M, int Nc, int K, int lda, int ldb,
             long sA, long sB, long sC)
{
    const u16* A  = Ag + (long)blockIdx.z * sA;
    const u16* Bt = Bg + (long)blockIdx.z * sB;

    __shared__ u16 As[8192];   // 128 rows x 64 cols bf16 (16 KB)
    __shared__ u16 Bs[8192];

    const int tid  = threadIdx.x;
    const int wave = tid >> 6;
    const int lane = tid & 63;
    const int arow0 = blockIdx.y * 128;
    const int brow0 = blockIdx.x * 128;
    const int wr = (wave >> 1) * 64;   // wave row offset in tile
    const int wc = (wave & 1) * 64;    // wave col offset in tile

    f32x4 zero = {0.f, 0.f, 0.f, 0.f};
    f32x4 acc[4][4];
#pragma unroll
    for (int i = 0; i < 4; i++)
#pragma unroll
        for (int j = 0; j < 4; j++) acc[i][j] = zero;

    const int kTiles = K >> 6;
    for (int kt = 0; kt < kTiles; ++kt) {
        // ---- stage 128x64 A and Bt tiles (16KB each), linear LDS dest,
        //      inverse-swizzled global source: gcol = kb ^ ((row&7)<<4)
#pragma unroll
        for (int it = 0; it < 4; ++it) {
            const int off  = it * 4096 + wave * 1024 + lane * 16;  // LDS byte
            const int row  = off >> 7;
            const int kb   = off & 127;
            const int gcol = kb ^ ((row & 7) << 4);
            gload_lds16((const char*)A  + ((long)(arow0 + row) * lda + kt * 64) * 2 + gcol,
                        (char*)As + it * 4096 + wave * 1024);
            gload_lds16((const char*)Bt + ((long)(brow0 + row) * ldb + kt * 64) * 2 + gcol,
                        (char*)Bs + it * 4096 + wave * 1024);
        }
        __syncthreads();

        // ---- compute: 2 k-steps of 32, 16 MFMA each per wave
#pragma unroll
        for (int kk = 0; kk < 2; ++kk) {
            bf16x8 av[4], bv[4];
            const int kbyte = kk * 64 + ((lane >> 4) << 4);  // byte off of 8 bf16
#pragma unroll
            for (int m = 0; m < 4; m++) {
                const int row = wr + m * 16 + (lane & 15);
                av[m] = *(const bf16x8*)((const char*)As + row * 128 + (kbyte ^ ((row & 7) << 4)));
            }
#pragma unroll
            for (int n = 0; n < 4; n++) {
                const int row = wc + n * 16 + (lane & 15);
                bv[n] = *(const bf16x8*)((const char*)Bs + row * 128 + (kbyte ^ ((row & 7) << 4)));
            }
#pragma unroll
            for (int m = 0; m < 4; m++)
#pragma unroll
                for (int n = 0; n < 4; n++)
                    acc[m][n] = __builtin_amdgcn_mfma_f32_16x16x32_bf16(av[m], bv[n], acc[m][n], 0, 0, 0);
        }
        __syncthreads();
    }

    // ---- epilogue. C/D layout: col = lane&15, row = (lane>>4)*4 + r  [m89/m91]
    const int r0 = (lane >> 4) << 2;
    const int cl = lane & 15;
#pragma unroll
    for (int m = 0; m < 4; m++) {
        const long gm = (long)arow0 + wr + m * 16 + r0;
#pragma unroll
        for (int n = 0; n < 4; n++) {
            const long gn = (long)brow0 + wc + n * 16 + cl;
            if (MODE == 0) {
                u16* O = (u16*)Cg + blockIdx.z * sC;
#pragma unroll
                for (int r = 0; r < 4; r++)
                    O[(gm + r) * Nc + gn] = f2bf(acc[m][n][r]);
            } else if (MODE == 1) {
                u16* O = (u16*)Cg;
                const long b = gm >> 10;
                const long t = gm & 1023;
                U16x4 u;
                u.x = f2bf(acc[m][n][0]); u.y = f2bf(acc[m][n][1]);
                u.z = f2bf(acc[m][n][2]); u.w = f2bf(acc[m][n][3]);
                *(U16x4*)(O + (b * 512 + gn) * 1024 + t) = u;
            } else {
                float* O = (float*)Cg + blockIdx.z * sC;
                const float bb = (MODE == 3) ? bias[gn] : 0.f;
#pragma unroll
                for (int r = 0; r < 4; r++)
                    O[(gm + r) * Nc + gn] = acc[m][n][r] + bb;
            }
        }
    }
}

// ---------------------------------------------------------------------------
// Row softmax over 512 fp32 logits (with 1/sqrt(512) scale), writing bf16 P
// IN-PLACE over the fp32 row (P row stride = 1024 u16 = fp32 row stride).
// One block (256 thr) per row; all reads precede all writes (block syncs).
// ---------------------------------------------------------------------------
__global__ __launch_bounds__(256)
void softmax_rows(float* __restrict__ S)
{
    const long r = blockIdx.x;
    float* row = S + r * 512;
    const int t = threadIdx.x;
    const int lane = t & 63, wave = t >> 6;
    const float scale = 0.04419417382415922f;  // 512^-0.5

    float a = row[t] * scale;
    float b = row[t + 256] * scale;

    float m = fmaxf(a, b);
#pragma unroll
    for (int o = 32; o; o >>= 1) m = fmaxf(m, __shfl_xor(m, o, 64));

    __shared__ float red[8];
    if (lane == 0) red[wave] = m;
    __syncthreads();
    m = fmaxf(fmaxf(red[0], red[1]), fmaxf(red[2], red[3]));

    float e0 = __expf(a - m), e1 = __expf(b - m);
    float s = e0 + e1;
#pragma unroll
    for (int o = 32; o; o >>= 1) s += __shfl_xor(s, o, 64);
    if (lane == 0) red[wave + 4] = s;
    __syncthreads();
    s = red[4] + red[5] + red[6] + red[7];
    const float inv = 1.f / s;

    u16* P = (u16*)row;   // bf16 row, ld (in u16) = 1024 relative to S base
    P[t]       = f2bf(e0 * inv);
    P[t + 256] = f2bf(e1 * inv);
}

// ---------------------------------------------------------------------------
extern "C" void kernel_launch(void* const* d_in, const int* in_sizes, int n_in,
                              void* d_out, int out_size, void* d_ws, size_t ws_size,
                              hipStream_t stream)
{
    (void)in_sizes; (void)n_in; (void)out_size; (void)ws_size;
    const float* x  = (const float*)d_in[0];
    const float* Wq = (const float*)d_in[1];
    const float* Wk = (const float*)d_in[2];
    const float* Wv = (const float*)d_in[3];
    const float* Wp = (const float*)d_in[4];
    const float* bp = (const float*)d_in[5];
    float* out = (float*)d_out;

    char* ws = (char*)d_ws;
    size_t o = 0;
    auto alloc = [&](size_t bytes) {
        char* p = ws + o;
        o = (o + bytes + 255) & ~(size_t)255;
        return p;
    };
    u16* xb  = (u16*)alloc((size_t)BB * TT * NN * 2);       // x bf16 [16384,512]
    u16* wqb = (u16*)alloc((size_t)NN * NN * 2);
    u16* wkb = (u16*)alloc((size_t)NN * NN * 2);
    u16* wvb = (u16*)alloc((size_t)NN * NN * 2);
    u16* wpb = (u16*)alloc((size_t)NN * NN * 2);
    u16* qb  = (u16*)alloc((size_t)BB * NN * TT * 2);       // q [B,N,T]
    u16* kb  = (u16*)alloc((size_t)BB * NN * TT * 2);       // k [B,N,T]
    u16* vb  = (u16*)alloc((size_t)BB * TT * NN * 2);       // v [B*T,N]
    float* S = (float*)alloc((size_t)BB * NN * NN * 4);     // logits fp32 / P bf16 in-place
    u16* px  = xb;   // reuse: xb dead after QKV GEMMs

    // conversions
    cvt_f32_bf16<<<dim3(2048), dim3(256), 0, stream>>>(x,  xb,  (BB * TT * NN) / 4);
    cvt_f32_bf16<<<dim3(128),  dim3(256), 0, stream>>>(Wq, wqb, (NN * NN) / 4);
    cvt_f32_bf16<<<dim3(128),  dim3(256), 0, stream>>>(Wk, wkb, (NN * NN) / 4);
    cvt_f32_bf16<<<dim3(128),  dim3(256), 0, stream>>>(Wv, wvb, (NN * NN) / 4);
    cvt_f32_bf16<<<dim3(128),  dim3(256), 0, stream>>>(Wp, wpb, (NN * NN) / 4);

    const dim3 blk(256);
    const dim3 g1(NN / 128, (BB * TT) / 128, 1);      // (4,128)

    // Q,K: transposed store -> [B,N,T]; V: natural -> [B*T,N]
    gemm_nt<1><<<g1, blk, 0, stream>>>(xb, wqb, qb, nullptr, BB*TT, NN, NN, NN, NN, 0, 0, 0);
    gemm_nt<1><<<g1, blk, 0, stream>>>(xb, wkb, kb, nullptr, BB*TT, NN, NN, NN, NN, 0, 0, 0);
    gemm_nt<0><<<g1, blk, 0, stream>>>(xb, wvb, vb, nullptr, BB*TT, NN, NN, NN, NN, 0, 0, 0);

    // S[b] = Q[b] K[b]^T  (K dim = T = 1024)
    const dim3 g2(NN / 128, NN / 128, BB);            // (4,4,16)
    gemm_nt<2><<<g2, blk, 0, stream>>>(qb, kb, S, nullptr, NN, NN, TT, TT, TT,
                                       (long)NN * TT, (long)NN * TT, (long)NN * NN);

    // softmax rows (scale folded in), bf16 P in-place (ldb = 1024 u16)
    softmax_rows<<<dim3(BB * NN), dim3(256), 0, stream>>>(S);

    // px[b,t,n] = sum_m v[b,m,t] * P[b,n,m] : A = V[b] [1024,512], Bt = P[b] ld 1024
    const dim3 g3(NN / 128, TT / 128, BB);            // (4,8,16)
    gemm_nt<0><<<g3, blk, 0, stream>>>(vb, (const u16*)S, px, nullptr, TT, NN, NN, NN, 1024,
                                       (long)TT * NN, (long)NN * 1024, (long)TT * NN);

    // out = px @ Wp^T + bp  (fp32)
    gemm_nt<3><<<g1, blk, 0, stream>>>(px, wpb, out, bp, BB*TT, NN, NN, NN, NN, 0, 0, 0);
}

// Round 2
// 205.567 us; speedup vs baseline: 1.0760x; 1.0760x over previous
//
#include <hip/hip_runtime.h>
#include <stdint.h>

// Problem constants: B=16, T=1024, N=512
#define BB 16
#define TT 1024
#define NN 512

typedef unsigned short u16;
typedef __bf16 bf16_t;
typedef bf16_t bf16x8 __attribute__((ext_vector_type(8)));
typedef float f32x4 __attribute__((ext_vector_type(4)));

struct alignas(8) U16x4 { u16 x, y, z, w; };
struct alignas(16) F32x4 { float x, y, z, w; };

__device__ __forceinline__ u16 f2bf(float f) {
    union { float f; uint32_t u; } v; v.f = f;
    uint32_t r = v.u + 0x7fffu + ((v.u >> 16) & 1u);
    return (u16)(r >> 16);
}

__device__ __forceinline__ void gload_lds16(const void* g, void* l) {
    __builtin_amdgcn_global_load_lds(
        (const __attribute__((address_space(1))) void*)g,
        (__attribute__((address_space(3))) void*)l, 16, 0, 0);
}

// ---------------------------------------------------------------------------
// fp32 -> bf16 (RTNE), vectorized x4, grid-stride
// ---------------------------------------------------------------------------
__global__ __launch_bounds__(256)
void cvt_f32_bf16(const float* __restrict__ in, u16* __restrict__ out, int n4) {
    int i = blockIdx.x * blockDim.x + threadIdx.x;
    int stride = gridDim.x * blockDim.x;
    for (int c = i; c < n4; c += stride) {
        F32x4 f = ((const F32x4*)in)[c];
        U16x4 u;
        u.x = f2bf(f.x); u.y = f2bf(f.y); u.z = f2bf(f.z); u.w = f2bf(f.w);
        ((U16x4*)out)[c] = u;
    }
}

// All 4 weights (each 512x512) -> one contiguous bf16 buffer [Wq;Wk;Wv;Wp]
__global__ __launch_bounds__(256)
void cvt_weights(const float* __restrict__ Wq, const float* __restrict__ Wk,
                 const float* __restrict__ Wv, const float* __restrict__ Wp,
                 u16* __restrict__ out) {
    const int c = blockIdx.x * 256 + threadIdx.x;   // 0..262143 (x4 chunks)
    const int w = c >> 16;                          // 65536 chunks per weight
    const int idx = c & 65535;
    const float* src = (w == 0) ? Wq : (w == 1) ? Wk : (w == 2) ? Wv : Wp;
    F32x4 f = ((const F32x4*)src)[idx];
    U16x4 u;
    u.x = f2bf(f.x); u.y = f2bf(f.y); u.z = f2bf(f.z); u.w = f2bf(f.w);
    ((U16x4*)out)[c] = u;
}

// ---------------------------------------------------------------------------
// NT GEMM: C[i,j] = sum_k A[i,k] * Bt[j,k]   (A: [M,K] ld=lda, Bt: [Nc,K] ld=ldb)
// bf16 inputs (raw u16), fp32 accum. 128x128 tile, BK=64, 4 waves (2x2),
// each wave 4x4 frags of mfma_f32_16x16x32_bf16.
// LDS staged via global_load_lds(16B), linear LDS dest + inverse-XOR-swizzled
// global source (m173 pattern) -> conflict-reduced ds_read_b128.
// MODE 0: bf16 natural store C[i*Nc+j]  (+ z*sC)
// MODE 2: fp32 natural store            (+ z*sC)
// MODE 3: fp32 natural store + bias[j]
// MODE 4: fused QKV routing: j<512 -> Q transposed [B,512,1024],
//         512<=j<1024 -> K transposed, j>=1024 -> V natural [B*T,512].
//         Cg = base of contiguous {Q, K, V} buffers.
// ---------------------------------------------------------------------------
template<int MODE>
__global__ __launch_bounds__(256)
void gemm_nt(const u16* __restrict__ Ag, const u16* __restrict__ Bg,
             void* __restrict__ Cg, const float* __restrict__ bias,
             int M, int Nc, int K, int lda, int ldb,
             long sA, long sB, long sC)
{
    const u16* A  = Ag + (long)blockIdx.z * sA;
    const u16* Bt = Bg + (long)blockIdx.z * sB;

    __shared__ u16 As[8192];   // 128 rows x 64 cols bf16 (16 KB)
    __shared__ u16 Bs[8192];

    const int tid  = threadIdx.x;
    const int wave = tid >> 6;
    const int lane = tid & 63;
    const int arow0 = blockIdx.y * 128;
    const int brow0 = blockIdx.x * 128;
    const int wr = (wave >> 1) * 64;   // wave row offset in tile
    const int wc = (wave & 1) * 64;    // wave col offset in tile

    f32x4 zero = {0.f, 0.f, 0.f, 0.f};
    f32x4 acc[4][4];
#pragma unroll
    for (int i = 0; i < 4; i++)
#pragma unroll
        for (int j = 0; j < 4; j++) acc[i][j] = zero;

    const int kTiles = K >> 6;
    for (int kt = 0; kt < kTiles; ++kt) {
        // ---- stage 128x64 A and Bt tiles (16KB each), linear LDS dest,
        //      inverse-swizzled global source: gcol = kb ^ ((row&7)<<4)
#pragma unroll
        for (int it = 0; it < 4; ++it) {
            const int off  = it * 4096 + wave * 1024 + lane * 16;  // LDS byte
            const int row  = off >> 7;
            const int kb   = off & 127;
            const int gcol = kb ^ ((row & 7) << 4);
            gload_lds16((const char*)A  + ((long)(arow0 + row) * lda + kt * 64) * 2 + gcol,
                        (char*)As + it * 4096 + wave * 1024);
            gload_lds16((const char*)Bt + ((long)(brow0 + row) * ldb + kt * 64) * 2 + gcol,
                        (char*)Bs + it * 4096 + wave * 1024);
        }
        __syncthreads();

        // ---- compute: 2 k-steps of 32, 16 MFMA each per wave
#pragma unroll
        for (int kk = 0; kk < 2; ++kk) {
            bf16x8 av[4], bv[4];
            const int kbyte = kk * 64 + ((lane >> 4) << 4);  // byte off of 8 bf16
#pragma unroll
            for (int m = 0; m < 4; m++) {
                const int row = wr + m * 16 + (lane & 15);
                av[m] = *(const bf16x8*)((const char*)As + row * 128 + (kbyte ^ ((row & 7) << 4)));
            }
#pragma unroll
            for (int n = 0; n < 4; n++) {
                const int row = wc + n * 16 + (lane & 15);
                bv[n] = *(const bf16x8*)((const char*)Bs + row * 128 + (kbyte ^ ((row & 7) << 4)));
            }
#pragma unroll
            for (int m = 0; m < 4; m++)
#pragma unroll
                for (int n = 0; n < 4; n++)
                    acc[m][n] = __builtin_amdgcn_mfma_f32_16x16x32_bf16(av[m], bv[n], acc[m][n], 0, 0, 0);
        }
        __syncthreads();
    }

    // ---- epilogue. C/D layout: col = lane&15, row = (lane>>4)*4 + r  [m89/m91]
    const int r0 = (lane >> 4) << 2;
    const int cl = lane & 15;
#pragma unroll
    for (int m = 0; m < 4; m++) {
        const long gm = (long)arow0 + wr + m * 16 + r0;
#pragma unroll
        for (int n = 0; n < 4; n++) {
            const long gn = (long)brow0 + wc + n * 16 + cl;
            if (MODE == 0) {
                u16* O = (u16*)Cg + blockIdx.z * sC;
#pragma unroll
                for (int r = 0; r < 4; r++)
                    O[(gm + r) * Nc + gn] = f2bf(acc[m][n][r]);
            } else if (MODE == 4) {
                const long b = gm >> 10;
                const long t = gm & 1023;
                if (gn < 1024) {       // Q or K: transposed store -> [B,512,1024]
                    u16* O = (u16*)Cg + (gn >> 9) * ((long)BB * NN * TT);
                    const long col = gn & 511;
                    U16x4 u;
                    u.x = f2bf(acc[m][n][0]); u.y = f2bf(acc[m][n][1]);
                    u.z = f2bf(acc[m][n][2]); u.w = f2bf(acc[m][n][3]);
                    *(U16x4*)(O + (b * 512 + col) * 1024 + t) = u;
                } else {               // V: natural store -> [B*T, 512]
                    u16* V = (u16*)Cg + 2L * BB * NN * TT;
                    const int vc = (int)gn - 1024;
#pragma unroll
                    for (int r = 0; r < 4; r++)
                        V[(gm + r) * NN + vc] = f2bf(acc[m][n][r]);
                }
            } else {
                float* O = (float*)Cg + blockIdx.z * sC;
                const float bb = (MODE == 3) ? bias[gn] : 0.f;
#pragma unroll
                for (int r = 0; r < 4; r++)
                    O[(gm + r) * Nc + gn] = acc[m][n][r] + bb;
            }
        }
    }
}

// ---------------------------------------------------------------------------
// Row softmax over 512 fp32 logits (with 1/sqrt(512) scale), writing bf16 P
// IN-PLACE over the fp32 row (P row stride = 1024 u16 = fp32 row stride).
// One block (256 thr) per row; all reads precede all writes (block syncs).
// ---------------------------------------------------------------------------
__global__ __launch_bounds__(256)
void softmax_rows(float* __restrict__ S)
{
    const long r = blockIdx.x;
    float* row = S + r * 512;
    const int t = threadIdx.x;
    const int lane = t & 63, wave = t >> 6;
    const float scale = 0.04419417382415922f;  // 512^-0.5

    float a = row[t] * scale;
    float b = row[t + 256] * scale;

    float m = fmaxf(a, b);
#pragma unroll
    for (int o = 32; o; o >>= 1) m = fmaxf(m, __shfl_xor(m, o, 64));

    __shared__ float red[8];
    if (lane == 0) red[wave] = m;
    __syncthreads();
    m = fmaxf(fmaxf(red[0], red[1]), fmaxf(red[2], red[3]));

    float e0 = __expf(a - m), e1 = __expf(b - m);
    float s = e0 + e1;
#pragma unroll
    for (int o = 32; o; o >>= 1) s += __shfl_xor(s, o, 64);
    if (lane == 0) red[wave + 4] = s;
    __syncthreads();
    s = red[4] + red[5] + red[6] + red[7];
    const float inv = 1.f / s;

    u16* P = (u16*)row;   // bf16 row, ld (in u16) = 1024 relative to S base
    P[t]       = f2bf(e0 * inv);
    P[t + 256] = f2bf(e1 * inv);
}

// ---------------------------------------------------------------------------
extern "C" void kernel_launch(void* const* d_in, const int* in_sizes, int n_in,
                              void* d_out, int out_size, void* d_ws, size_t ws_size,
                              hipStream_t stream)
{
    (void)in_sizes; (void)n_in; (void)out_size; (void)ws_size;
    const float* x  = (const float*)d_in[0];
    const float* Wq = (const float*)d_in[1];
    const float* Wk = (const float*)d_in[2];
    const float* Wv = (const float*)d_in[3];
    const float* Wp = (const float*)d_in[4];
    const float* bp = (const float*)d_in[5];
    float* out = (float*)d_out;

    char* ws = (char*)d_ws;
    size_t o = 0;
    auto alloc = [&](size_t bytes) {
        char* p = ws + o;
        o = (o + bytes + 255) & ~(size_t)255;
        return p;
    };
    u16* xb  = (u16*)alloc((size_t)BB * TT * NN * 2);       // x bf16 [16384,512]
    u16* wb  = (u16*)alloc((size_t)4 * NN * NN * 2);        // [Wq;Wk;Wv;Wp] bf16
    u16* qkv = (u16*)alloc((size_t)3 * BB * NN * TT * 2);   // Q[B,N,T], K[B,N,T], V[B*T,N]
    float* S = (float*)alloc((size_t)BB * NN * NN * 4);     // logits fp32 / P bf16 in-place
    u16* px  = xb;   // reuse: xb dead after QKV GEMM

    const u16* qb  = qkv;
    const u16* kbp = qkv + (size_t)BB * NN * TT;
    const u16* vb  = qkv + (size_t)2 * BB * NN * TT;
    const u16* wpb = wb + (size_t)3 * NN * NN;

    // conversions (2 launches)
    cvt_f32_bf16<<<dim3(2048), dim3(256), 0, stream>>>(x, xb, (BB * TT * NN) / 4);
    cvt_weights<<<dim3(1024), dim3(256), 0, stream>>>(Wq, Wk, Wv, Wp, wb);

    const dim3 blk(256);

    // Fused QKV projection: [16384,512] x [1536,512]^T, routed epilogue
    const dim3 gq(12, 128, 1);
    gemm_nt<4><<<gq, blk, 0, stream>>>(xb, wb, qkv, nullptr,
                                       BB * TT, 1536, NN, NN, NN, 0, 0, 0);

    // S[b] = Q[b] K[b]^T  (contraction over T = 1024)
    const dim3 g2(NN / 128, NN / 128, BB);            // (4,4,16)
    gemm_nt<2><<<g2, blk, 0, stream>>>(qb, kbp, S, nullptr, NN, NN, TT, TT, TT,
                                       (long)NN * TT, (long)NN * TT, (long)NN * NN);

    // softmax rows (scale folded in), bf16 P in-place (ldb = 1024 u16)
    softmax_rows<<<dim3(BB * NN), dim3(256), 0, stream>>>(S);

    // px[b,t,n] = sum_m P[b,n,m] v[b,m,t] : A = V[b] [1024,512], Bt = P[b] ld 1024
    const dim3 g3(NN / 128, TT / 128, BB);            // (4,8,16)
    gemm_nt<0><<<g3, blk, 0, stream>>>(vb, (const u16*)S, px, nullptr, TT, NN, NN, NN, 1024,
                                       (long)TT * NN, (long)NN * 1024, (long)TT * NN);

    // out = px @ Wp^T + bp  (fp32)
    const dim3 g1(NN / 128, (BB * TT) / 128, 1);      // (4,128)
    gemm_nt<3><<<g1, blk, 0, stream>>>(px, wpb, out, bp, BB * TT, NN, NN, NN, NN, 0, 0, 0);
}

// Round 3
// 189.929 us; speedup vs baseline: 1.1646x; 1.0823x over previous
//
#include <hip/hip_runtime.h>
#include <stdint.h>

// Problem constants: B=16, T=1024, N=512
#define BB 16
#define TT 1024
#define NN 512

typedef unsigned short u16;
typedef __bf16 bf16_t;
typedef bf16_t bf16x8 __attribute__((ext_vector_type(8)));
typedef float f32x4 __attribute__((ext_vector_type(4)));

struct alignas(8) U16x4 { u16 x, y, z, w; };
struct alignas(16) F32x4 { float x, y, z, w; };

__device__ __forceinline__ u16 f2bf(float f) {
    union { float f; uint32_t u; } v; v.f = f;
    uint32_t r = v.u + 0x7fffu + ((v.u >> 16) & 1u);
    return (u16)(r >> 16);
}

__device__ __forceinline__ void gload_lds16(const void* g, void* l) {
    __builtin_amdgcn_global_load_lds(
        (const __attribute__((address_space(1))) void*)g,
        (__attribute__((address_space(3))) void*)l, 16, 0, 0);
}

// Bijective XCD-aware swizzle (m204): blocks sharing an A row-panel land on
// the same XCD's L2. Logical tile id is row-panel-major (col-fastest).
__device__ __forceinline__ void xcd_swizzle(int gx, int gy, int& bx, int& by) {
    const int nwg  = gx * gy;
    const int orig = by * gx + bx;
    const int q = nwg >> 3, r = nwg & 7;
    const int xcd = orig & 7, loc = orig >> 3;
    const int swz = (xcd < r ? xcd * (q + 1) : r * (q + 1) + (xcd - r) * q) + loc;
    bx = swz % gx;
    by = swz / gx;
}

// ---------------------------------------------------------------------------
// fp32 -> bf16 (RTNE), vectorized x4, grid-stride
// ---------------------------------------------------------------------------
__global__ __launch_bounds__(256)
void cvt_f32_bf16(const float* __restrict__ in, u16* __restrict__ out, int n4) {
    int i = blockIdx.x * blockDim.x + threadIdx.x;
    int stride = gridDim.x * blockDim.x;
    for (int c = i; c < n4; c += stride) {
        F32x4 f = ((const F32x4*)in)[c];
        U16x4 u;
        u.x = f2bf(f.x); u.y = f2bf(f.y); u.z = f2bf(f.z); u.w = f2bf(f.w);
        ((U16x4*)out)[c] = u;
    }
}

// All 4 weights (each 512x512) -> one contiguous bf16 buffer [Wq;Wk;Wv;Wp]
__global__ __launch_bounds__(256)
void cvt_weights(const float* __restrict__ Wq, const float* __restrict__ Wk,
                 const float* __restrict__ Wv, const float* __restrict__ Wp,
                 u16* __restrict__ out) {
    const int c = blockIdx.x * 256 + threadIdx.x;   // 0..262143 (x4 chunks)
    const int w = c >> 16;                          // 65536 chunks per weight
    const int idx = c & 65535;
    const float* src = (w == 0) ? Wq : (w == 1) ? Wk : (w == 2) ? Wv : Wp;
    F32x4 f = ((const F32x4*)src)[idx];
    U16x4 u;
    u.x = f2bf(f.x); u.y = f2bf(f.y); u.z = f2bf(f.z); u.w = f2bf(f.w);
    ((U16x4*)out)[c] = u;
}

// ---------------------------------------------------------------------------
// NT GEMM: C[i,j] = sum_k A[i,k] * Bt[j,k]   (A: [M,K] ld=lda, Bt: [Nc,K] ld=ldb)
// bf16 inputs (raw u16), fp32 accum. 128x128 tile, BK=64, 4 waves (2x2),
// each wave 4x4 frags of mfma_f32_16x16x32_bf16. XCD-swizzled block mapping.
// LDS staged via global_load_lds(16B), linear LDS dest + inverse-XOR-swizzled
// global source (m173 pattern) -> conflict-reduced ds_read_b128.
// MODE 0: bf16 natural store C[i*Nc+j]  (+ z*sC)
// MODE 2: fp32 natural store            (+ z*sC)
// MODE 3: fp32 natural store + bias[j]
// MODE 4: fused QKV routing: j<512 -> Q transposed [B,512,1024],
//         512<=j<1024 -> K transposed, j>=1024 -> V natural [B*T,512].
// SPLITK: blockIdx.z = half*16 + b; A/B advance half*K in the k dim;
//         C offset stays blockIdx.z*sC (partial buffers stacked).
// ---------------------------------------------------------------------------
template<int MODE, int SPLITK>
__global__ __launch_bounds__(256)
void gemm_nt(const u16* __restrict__ Ag, const u16* __restrict__ Bg,
             void* __restrict__ Cg, const float* __restrict__ bias,
             int M, int Nc, int K, int lda, int ldb,
             long sA, long sB, long sC)
{
    int zb = blockIdx.z, kof = 0;
    if (SPLITK) { kof = (zb >> 4) * K; zb &= 15; }
    const u16* A  = Ag + (long)zb * sA + kof;
    const u16* Bt = Bg + (long)zb * sB + kof;

    __shared__ u16 As[8192];   // 128 rows x 64 cols bf16 (16 KB)
    __shared__ u16 Bs[8192];

    int bx = blockIdx.x, by = blockIdx.y;
    xcd_swizzle(gridDim.x, gridDim.y, bx, by);

    const int tid  = threadIdx.x;
    const int wave = tid >> 6;
    const int lane = tid & 63;
    const int arow0 = by * 128;
    const int brow0 = bx * 128;
    const int wr = (wave >> 1) * 64;   // wave row offset in tile
    const int wc = (wave & 1) * 64;    // wave col offset in tile

    f32x4 zero = {0.f, 0.f, 0.f, 0.f};
    f32x4 acc[4][4];
#pragma unroll
    for (int i = 0; i < 4; i++)
#pragma unroll
        for (int j = 0; j < 4; j++) acc[i][j] = zero;

    const int kTiles = K >> 6;
    for (int kt = 0; kt < kTiles; ++kt) {
        // ---- stage 128x64 A and Bt tiles (16KB each), linear LDS dest,
        //      inverse-swizzled global source: gcol = kb ^ ((row&7)<<4)
#pragma unroll
        for (int it = 0; it < 4; ++it) {
            const int off  = it * 4096 + wave * 1024 + lane * 16;  // LDS byte
            const int row  = off >> 7;
            const int kb   = off & 127;
            const int gcol = kb ^ ((row & 7) << 4);
            gload_lds16((const char*)A  + ((long)(arow0 + row) * lda + kt * 64) * 2 + gcol,
                        (char*)As + it * 4096 + wave * 1024);
            gload_lds16((const char*)Bt + ((long)(brow0 + row) * ldb + kt * 64) * 2 + gcol,
                        (char*)Bs + it * 4096 + wave * 1024);
        }
        __syncthreads();

        // ---- compute: 2 k-steps of 32, 16 MFMA each per wave
#pragma unroll
        for (int kk = 0; kk < 2; ++kk) {
            bf16x8 av[4], bv[4];
            const int kbyte = kk * 64 + ((lane >> 4) << 4);  // byte off of 8 bf16
#pragma unroll
            for (int m = 0; m < 4; m++) {
                const int row = wr + m * 16 + (lane & 15);
                av[m] = *(const bf16x8*)((const char*)As + row * 128 + (kbyte ^ ((row & 7) << 4)));
            }
#pragma unroll
            for (int n = 0; n < 4; n++) {
                const int row = wc + n * 16 + (lane & 15);
                bv[n] = *(const bf16x8*)((const char*)Bs + row * 128 + (kbyte ^ ((row & 7) << 4)));
            }
#pragma unroll
            for (int m = 0; m < 4; m++)
#pragma unroll
                for (int n = 0; n < 4; n++)
                    acc[m][n] = __builtin_amdgcn_mfma_f32_16x16x32_bf16(av[m], bv[n], acc[m][n], 0, 0, 0);
        }
        __syncthreads();
    }

    // ---- epilogue. C/D layout: col = lane&15, row = (lane>>4)*4 + r  [m89/m91]
    const int r0 = (lane >> 4) << 2;
    const int cl = lane & 15;
#pragma unroll
    for (int m = 0; m < 4; m++) {
        const long gm = (long)arow0 + wr + m * 16 + r0;
#pragma unroll
        for (int n = 0; n < 4; n++) {
            const long gn = (long)brow0 + wc + n * 16 + cl;
            if (MODE == 0) {
                u16* O = (u16*)Cg + blockIdx.z * sC;
#pragma unroll
                for (int r = 0; r < 4; r++)
                    O[(gm + r) * Nc + gn] = f2bf(acc[m][n][r]);
            } else if (MODE == 4) {
                const long b = gm >> 10;
                const long t = gm & 1023;
                if (gn < 1024) {       // Q or K: transposed store -> [B,512,1024]
                    u16* O = (u16*)Cg + (gn >> 9) * ((long)BB * NN * TT);
                    const long col = gn & 511;
                    U16x4 u;
                    u.x = f2bf(acc[m][n][0]); u.y = f2bf(acc[m][n][1]);
                    u.z = f2bf(acc[m][n][2]); u.w = f2bf(acc[m][n][3]);
                    *(U16x4*)(O + (b * 512 + col) * 1024 + t) = u;
                } else {               // V: natural store -> [B*T, 512]
                    u16* V = (u16*)Cg + 2L * BB * NN * TT;
                    const int vc = (int)gn - 1024;
#pragma unroll
                    for (int r = 0; r < 4; r++)
                        V[(gm + r) * NN + vc] = f2bf(acc[m][n][r]);
                }
            } else {
                float* O = (float*)Cg + blockIdx.z * sC;
                const float bb = (MODE == 3) ? bias[gn] : 0.f;
#pragma unroll
                for (int r = 0; r < 4; r++)
                    O[(gm + r) * Nc + gn] = acc[m][n][r] + bb;
            }
        }
    }
}

// ---------------------------------------------------------------------------
// Row softmax over 512 logits = S0+S1 (split-K partials), scaled by 512^-0.5,
// writing bf16 P IN-PLACE over the S0 fp32 row (P row stride = 1024 u16).
// One block (256 thr) per row; all reads precede all writes (block syncs).
// ---------------------------------------------------------------------------
__global__ __launch_bounds__(256)
void softmax_rows(float* __restrict__ S0, const float* __restrict__ S1)
{
    const long r = blockIdx.x;
    float* row0 = S0 + r * 512;
    const float* row1 = S1 + r * 512;
    const int t = threadIdx.x;
    const int lane = t & 63, wave = t >> 6;
    const float scale = 0.04419417382415922f;  // 512^-0.5

    float a = (row0[t]       + row1[t])       * scale;
    float b = (row0[t + 256] + row1[t + 256]) * scale;

    float m = fmaxf(a, b);
#pragma unroll
    for (int o = 32; o; o >>= 1) m = fmaxf(m, __shfl_xor(m, o, 64));

    __shared__ float red[8];
    if (lane == 0) red[wave] = m;
    __syncthreads();
    m = fmaxf(fmaxf(red[0], red[1]), fmaxf(red[2], red[3]));

    float e0 = __expf(a - m), e1 = __expf(b - m);
    float s = e0 + e1;
#pragma unroll
    for (int o = 32; o; o >>= 1) s += __shfl_xor(s, o, 64);
    if (lane == 0) red[wave + 4] = s;
    __syncthreads();
    s = red[4] + red[5] + red[6] + red[7];
    const float inv = 1.f / s;

    u16* P = (u16*)row0;   // bf16 row, ld (in u16) = 1024 relative to S0 base
    P[t]       = f2bf(e0 * inv);
    P[t + 256] = f2bf(e1 * inv);
}

// ---------------------------------------------------------------------------
extern "C" void kernel_launch(void* const* d_in, const int* in_sizes, int n_in,
                              void* d_out, int out_size, void* d_ws, size_t ws_size,
                              hipStream_t stream)
{
    (void)in_sizes; (void)n_in; (void)out_size; (void)ws_size;
    const float* x  = (const float*)d_in[0];
    const float* Wq = (const float*)d_in[1];
    const float* Wk = (const float*)d_in[2];
    const float* Wv = (const float*)d_in[3];
    const float* Wp = (const float*)d_in[4];
    const float* bp = (const float*)d_in[5];
    float* out = (float*)d_out;

    char* ws = (char*)d_ws;
    size_t o = 0;
    auto alloc = [&](size_t bytes) {
        char* p = ws + o;
        o = (o + bytes + 255) & ~(size_t)255;
        return p;
    };
    u16* xb  = (u16*)alloc((size_t)BB * TT * NN * 2);       // x bf16 [16384,512]
    u16* wb  = (u16*)alloc((size_t)4 * NN * NN * 2);        // [Wq;Wk;Wv;Wp] bf16
    u16* qkv = (u16*)alloc((size_t)3 * BB * NN * TT * 2);   // Q[B,N,T], K[B,N,T], V[B*T,N]
    float* S = (float*)alloc((size_t)2 * BB * NN * NN * 4); // split-K partials [2][B,512,512]
    u16* px  = xb;   // reuse: xb dead after QKV GEMM

    const u16* qb  = qkv;
    const u16* kbp = qkv + (size_t)BB * NN * TT;
    const u16* vb  = qkv + (size_t)2 * BB * NN * TT;
    const u16* wpb = wb + (size_t)3 * NN * NN;
    float* S1 = S + (size_t)BB * NN * NN;

    // conversions (2 launches)
    cvt_f32_bf16<<<dim3(2048), dim3(256), 0, stream>>>(x, xb, (BB * TT * NN) / 4);
    cvt_weights<<<dim3(1024), dim3(256), 0, stream>>>(Wq, Wk, Wv, Wp, wb);

    const dim3 blk(256);

    // Fused QKV projection: [16384,512] x [1536,512]^T, routed epilogue
    const dim3 gq(12, 128, 1);
    gemm_nt<4, 0><<<gq, blk, 0, stream>>>(xb, wb, qkv, nullptr,
                                          BB * TT, 1536, NN, NN, NN, 0, 0, 0);

    // S[half][b] = Q[b][:, half*512:+512] K[b][:, same]^T  (split-K=2 over T)
    const dim3 g2(NN / 128, NN / 128, 2 * BB);        // (4,4,32)
    gemm_nt<2, 1><<<g2, blk, 0, stream>>>(qb, kbp, S, nullptr, NN, NN, TT / 2, TT, TT,
                                          (long)NN * TT, (long)NN * TT, (long)NN * NN);

    // softmax rows (sums partials, scale folded in), bf16 P in-place over S0
    softmax_rows<<<dim3(BB * NN), dim3(256), 0, stream>>>(S, S1);

    // px[b,t,n] = sum_m P[b,n,m] v[b,m,t] : A = V[b] [1024,512], Bt = P[b] ld 1024
    const dim3 g3(NN / 128, TT / 128, BB);            // (4,8,16)
    gemm_nt<0, 0><<<g3, blk, 0, stream>>>(vb, (const u16*)S, px, nullptr, TT, NN, NN, NN, 1024,
                                          (long)TT * NN, (long)NN * 1024, (long)TT * NN);

    // out = px @ Wp^T + bp  (fp32)
    const dim3 g1(NN / 128, (BB * TT) / 128, 1);      // (4,128)
    gemm_nt<3, 0><<<g1, blk, 0, stream>>>(px, wpb, out, bp, BB * TT, NN, NN, NN, NN, 0, 0, 0);
}